// Round 6
// baseline (238.998 us; speedup 1.0000x reference)
//
#include <hip/hip_runtime.h>

// SchroederReverb: 4 series allpass (N=225,556,441,341, g=0.7) then 4 parallel
// feedback combs (N=1116,1188,1277,1356, g=.84,.82,.80,.78) summed.
//
// Verified closed form (rounds 3-5): the allpass chain is the identity plus a
// zero-head transient; composing all 4 stages:
//     s[n] = x[n] - pw[n/225]*x[n%225] - pw[n/556]*h1[n%556],
// pw[m] = (-0.7)^m (inline exp2f, verified round-5), h1[m] head rows [0,556):
//     h1[m<225]=0; h1[225<=m<450]=x[m]+0.7x[m-225]; h1[m>=450]=x[m]-0.49x[m-450].
//
// Round-12 (this round), two traffic cuts on the materialized-s design:
//  1. s stored as FP16 (rel err ~5e-4; output err ~4e-3 << 0.0625 tol):
//     halves prep-write + all comb march reads. s = 32 MiB in ws.
//  2. prep fused INTO comb1: comb1's march visits every s row in [1116,T)
//     exactly once (bijection n = k*1116 + r, k>=1; rows <1116 never read by
//     any comb since k=0 is forced zero) -> march computes s from x inline
//     (x stream + gathers in L2-hot first 556 x rows) and writes fp16 s as a
//     byproduct. Standalone prep kernel (134 MB round-trip) disappears.
// Cache-level traffic: 871 -> ~670 MB.
// Combs keep the proven segmented scan: single-chain items (item = chain r,
// wave = one row), S=8 waves/block, LDS carries, affine store fixup
// y_true[j] = y[j] + a^(j+1)*Yin, item loop, grid 1024.
// comb1 writes out, combs 2-4 RMW. NO atomics (prior session: 2.2 TB/s).
// __launch_bounds__ arg2 = min BLOCKS/CU (verified round-7: (512,4)->cap 64).
//
// Comb semantics (identical to passing rounds 1-11):
//   y[k=0]=0; y[k] = g*y[k-1] + s[k]   per chain (k>=1)
//
// Coverage (S=8): S*L >= Kmax, (S-1)*L <= Kmin:
//   comb1 N=1116 K=118/117: L=15   comb2 N=1188 K=111/110: L=14
//   comb3 N=1277 K=103/102: L=13   comb4 N=1356 K= 97/ 96: L=13

constexpr int W = 128;

template <int V> struct fv { float d[V]; };

template <int V>
__device__ __forceinline__ fv<V> fv_zero() {
  fv<V> r;
#pragma unroll
  for (int c = 0; c < V; ++c) r.d[c] = 0.f;
  return r;
}
using fv2 = fv<2>;
using fv4 = fv<4>;

struct h2 { _Float16 d[2]; };               // fp16 pair (4 B)

// ---- half march: y[k] = a*y[k-1] + s[n], s preloaded fp16 -----------------
template <int K, bool PRED>
__device__ __forceinline__
void hmarch_blk(const h2* __restrict__ sb, int n0, int N, int lane,
                int Tn, float a, fv2& yp, fv2* __restrict__ y) {
  h2 xs[K];
#pragma unroll
  for (int u = 0; u < K; ++u) {
    const int n = n0 + u * N;
    if (!PRED || n < Tn) {
      xs[u] = sb[n * 64 + lane];
    } else {
      xs[u].d[0] = (_Float16)0.f;
      xs[u].d[1] = (_Float16)0.f;
    }
  }
#pragma unroll
  for (int u = 0; u < K; ++u) {
    yp.d[0] = fmaf(a, yp.d[0], (float)xs[u].d[0]);
    yp.d[1] = fmaf(a, yp.d[1], (float)xs[u].d[1]);
    y[u] = yp;
  }
}

template <int CNT, bool PRED, int U>
__device__ __forceinline__
void hmarch_seg(const h2* __restrict__ sb, int n0, int N, int lane,
                int Tn, float a, fv2& yp, fv2* __restrict__ y) {
  constexpr int NB = CNT / U, R = CNT % U;
#pragma unroll
  for (int b = 0; b < NB; ++b)
    hmarch_blk<U, PRED>(sb, n0 + b * U * N, N, lane, Tn, a, yp, y + b * U);
  if constexpr (R > 0)
    hmarch_blk<R, PRED>(sb, n0 + NB * U * N, N, lane, Tn, a, yp, y + NB * U);
}

// ---- compute march (comb1): s computed from x inline, written as fp16 -----
template <int K, bool PRED>
__device__ __forceinline__
void cmarch_blk(const fv2* __restrict__ x, h2* __restrict__ sb,
                int n0, int N, int lane, int Tn, float a,
                fv2& yp, fv2* __restrict__ y) {
  fv2 xs[K], t1[K], t2[K];
  float p1[K], p2[K];
#pragma unroll
  for (int u = 0; u < K; ++u) {
    const int n = n0 + u * N;
    const bool ok = !PRED || n < Tn;
    const int q1 = n / 225, r1 = n - q1 * 225;    // magic-mul (const divisor)
    const int q2 = n / 556, r2 = n - q2 * 556;
    xs[u] = ok ? x[n * 64 + lane] : fv_zero<2>();
    t1[u] = x[r1 * 64 + lane];                    // L2-hot (225 rows)
    if (r2 < 225) {                               // wave-uniform branch
      t2[u] = fv_zero<2>();
    } else {                                      // h1(r2) from x rows (hot)
      fv2 b = x[r2 * 64 + lane];
      const int   d = (r2 < 450) ? 225 : 450;
      const float c = (r2 < 450) ? 0.7f : -0.49f; // -(-0.7)^1 / -(-0.7)^2
      fv2 tt = x[(r2 - d) * 64 + lane];
      t2[u].d[0] = fmaf(c, tt.d[0], b.d[0]);
      t2[u].d[1] = fmaf(c, tt.d[1], b.d[1]);
    }
    const float LG = -0.5145731728297583f;        // log2(0.7)
    const float m1 = exp2f((float)q1 * LG);
    const float m2 = exp2f((float)q2 * LG);
    p1[u] = ok ? ((q1 & 1) ? -m1 : m1) : 0.f;     // (-0.7)^q1 (0 if masked)
    p2[u] = ok ? ((q2 & 1) ? -m2 : m2) : 0.f;
  }
#pragma unroll
  for (int u = 0; u < K; ++u) {
    const int n = n0 + u * N;
    fv2 s;
    s.d[0] = fmaf(-p2[u], t2[u].d[0], fmaf(-p1[u], t1[u].d[0], xs[u].d[0]));
    s.d[1] = fmaf(-p2[u], t2[u].d[1], fmaf(-p1[u], t1[u].d[1], xs[u].d[1]));
    if (!PRED || n < Tn) {
      h2 hh;
      hh.d[0] = (_Float16)s.d[0];
      hh.d[1] = (_Float16)s.d[1];
      sb[n * 64 + lane] = hh;                     // s byproduct (fp16)
    }
    yp.d[0] = fmaf(a, yp.d[0], s.d[0]);           // comb1 uses fp32 s (free)
    yp.d[1] = fmaf(a, yp.d[1], s.d[1]);
    y[u] = yp;
  }
}

template <int CNT, bool PRED, int U>
__device__ __forceinline__
void cmarch_seg(const fv2* __restrict__ x, h2* __restrict__ sb,
                int n0, int N, int lane, int Tn, float a,
                fv2& yp, fv2* __restrict__ y) {
  constexpr int NB = CNT / U, R = CNT % U;
#pragma unroll
  for (int b = 0; b < NB; ++b)
    cmarch_blk<U, PRED>(x, sb, n0 + b * U * N, N, lane, Tn, a, yp, y + b * U);
  if constexpr (R > 0)
    cmarch_blk<R, PRED>(x, sb, n0 + NB * U * N, N, lane, Tn, a, yp, y + NB * U);
}

// ---- store pass: y_true[j] = y[j] + a^(j+1)*Yin  (MODE 2: += out) ---------
template <int MODE, int K, bool PRED>
__device__ __forceinline__
void fstore_blk(fv2* __restrict__ out, int n0, int N, int lane, int Tn,
                float a, fv2 Yin, const fv2* __restrict__ y, float& p) {
  fv2 os[K];
  if constexpr (MODE == 2) {
#pragma unroll
    for (int u = 0; u < K; ++u) {
      const int n = n0 + u * N;
      os[u] = (!PRED || n < Tn) ? out[n * 64 + lane] : fv_zero<2>();
    }
  }
#pragma unroll
  for (int u = 0; u < K; ++u) {
    const int n = n0 + u * N;
    fv2 v;
#pragma unroll
    for (int c = 0; c < 2; ++c) {
      v.d[c] = fmaf(p, Yin.d[c], y[u].d[c]);
      if constexpr (MODE == 2) v.d[c] += os[u].d[c];
    }
    if (!PRED || n < Tn) out[n * 64 + lane] = v;
    p *= a;
  }
}

template <int MODE, int CNT, bool PRED, int U>
__device__ __forceinline__
void fstore_seg(fv2* __restrict__ out, int n0, int N, int lane, int Tn,
                float a, fv2 Yin, const fv2* __restrict__ y, float p0) {
  constexpr int NB = CNT / U, R = CNT % U;
  float p = p0;
#pragma unroll
  for (int b = 0; b < NB; ++b)
    fstore_blk<MODE, U, PRED>(out, n0 + b * U * N, N, lane, Tn, a, Yin,
                              y + b * U, p);
  if constexpr (R > 0)
    fstore_blk<MODE, R, PRED>(out, n0 + NB * U * N, N, lane, Tn, a, Yin,
                              y + NB * U, p);
}

// ---- comb1 fused with s-generation (item = chain, wave = one row) ----------
template <int S, int L, int UM, int US>
__global__ __launch_bounds__(S * 64, 2)
void fcomb1(const fv2* __restrict__ x, h2* __restrict__ sb,
            fv2* __restrict__ out, int N, float g, float aL, int T) {
  const float a = g;
  __shared__ fv2 C[S][64];
  const int tid = threadIdx.x;
  const int s  = tid >> 6;
  const int l6 = tid & 63;

  for (int item = blockIdx.x; item < N; item += gridDim.x) {
    const int r  = item;
    const int n0 = s * L * N + r;

    fv2 y[L];
    fv2 yp = fv_zero<2>();

    if (s == 0) {
      y[0] = fv_zero<2>();                  // y[k=0] forced to 0, no s write
      cmarch_seg<L - 1, false, UM>(x, sb, n0 + N, N, l6, T, a, yp, y + 1);
    } else if (s < S - 1) {
      cmarch_seg<L, false, UM>(x, sb, n0, N, l6, T, a, yp, y);
    } else {
      cmarch_seg<L, true, UM>(x, sb, n0, N, l6, T, a, yp, y);
    }
    C[s][l6] = yp;
    __syncthreads();

    fv2 Yin = fv_zero<2>();
    for (int j = 0; j < s; ++j) {
#pragma unroll
      for (int c = 0; c < 2; ++c)
        Yin.d[c] = fmaf(aL, Yin.d[c], C[j][l6].d[c]);
    }
    __syncthreads();                        // C reusable by next item

    if (s < S - 1)
      fstore_seg<1, L, false, US>(out, n0, N, l6, T, a, Yin, y, a);
    else
      fstore_seg<1, L, true, US>(out, n0, N, l6, T, a, Yin, y, a);
  }
}

// ---- combs 2-4: fp16 s march + RMW store -----------------------------------
template <int S, int L, int UM, int US>
__global__ __launch_bounds__(S * 64, 3)
void fcombh(const h2* __restrict__ sb, fv2* __restrict__ out,
            int N, float g, float aL, int T) {
  const float a = g;
  __shared__ fv2 C[S][64];
  const int tid = threadIdx.x;
  const int s  = tid >> 6;
  const int l6 = tid & 63;

  for (int item = blockIdx.x; item < N; item += gridDim.x) {
    const int r  = item;
    const int n0 = s * L * N + r;

    fv2 y[L];
    fv2 yp = fv_zero<2>();

    if (s == 0) {
      y[0] = fv_zero<2>();                  // y[k=0] forced to 0
      hmarch_seg<L - 1, false, UM>(sb, n0 + N, N, l6, T, a, yp, y + 1);
    } else if (s < S - 1) {
      hmarch_seg<L, false, UM>(sb, n0, N, l6, T, a, yp, y);
    } else {
      hmarch_seg<L, true, UM>(sb, n0, N, l6, T, a, yp, y);
    }
    C[s][l6] = yp;
    __syncthreads();

    fv2 Yin = fv_zero<2>();
    for (int j = 0; j < s; ++j) {
#pragma unroll
      for (int c = 0; c < 2; ++c)
        Yin.d[c] = fmaf(aL, Yin.d[c], C[j][l6].d[c]);
    }
    __syncthreads();                        // C reusable by next item

    if (s < S - 1)
      fstore_seg<2, L, false, US>(out, n0, N, l6, T, a, Yin, y, a);
    else
      fstore_seg<2, L, true, US>(out, n0, N, l6, T, a, Yin, y, a);
  }
}

// ---- generic fallback (any T): original full recurrence pipeline -----------
constexpr int W2 = 64;
template <int MODE, bool STORE>
__device__ __forceinline__
void g_march(const float2* __restrict__ in, float2* __restrict__ out,
             int n, int N, int cnt, int T, int lane, float g, float a,
             float2& xp, float2& yp) {
  for (int j = 0; j < cnt; ++j) {
    float2 x = (n < T) ? in[n * W2 + lane] : make_float2(0.f, 0.f);
    float ux = (MODE == 0) ? fmaf(g, xp.x, x.x) : x.x;
    float uy = (MODE == 0) ? fmaf(g, xp.y, x.y) : x.y;
    yp.x = fmaf(a, yp.x, ux);
    yp.y = fmaf(a, yp.y, uy);
    xp = x;
    if (STORE && n < T) {
      float2 v = yp;
      if (MODE == 2) { v.x += out[n * W2 + lane].x; v.y += out[n * W2 + lane].y; }
      out[n * W2 + lane] = v;
    }
    n += N;
  }
}

template <int MODE>
__global__ __launch_bounds__(1024)
void stage_gen(const float2* __restrict__ in, float2* __restrict__ out,
               int N, float g, float aL, int L, int T) {
  const float a = (MODE == 0) ? -g : g;
  __shared__ float2 C[16][W2];
  const int tid = threadIdx.x, s = tid >> 6, lane = tid & 63;
  const int r = blockIdx.x;
  if (r >= T) return;
  const int n0 = s * L * N + r;
  if (s == 0) {
    float2 xp = make_float2(0.f, 0.f), yp = make_float2(0.f, 0.f);
    if (MODE == 0) xp = in[r * W2 + lane];
    if (MODE != 2) out[r * W2 + lane] = make_float2(0.f, 0.f);
    g_march<MODE, true>(in, out, r + N, N, L - 1, T, lane, g, a, xp, yp);
    C[0][lane] = yp;
    __syncthreads();
    return;
  }
  {
    float2 xp = make_float2(0.f, 0.f), yp = make_float2(0.f, 0.f);
    if (MODE == 0) xp = in[(n0 - N) * W2 + lane];
    g_march<MODE, false>(in, out, n0, N, L, T, lane, g, a, xp, yp);
    C[s][lane] = yp;
  }
  __syncthreads();
  float2 Yin = make_float2(0.f, 0.f);
  for (int j = 0; j < s; ++j) {
    Yin.x = fmaf(aL, Yin.x, C[j][lane].x);
    Yin.y = fmaf(aL, Yin.y, C[j][lane].y);
  }
  float2 xp = make_float2(0.f, 0.f), yp = Yin;
  if (MODE == 0) xp = in[(n0 - N) * W2 + lane];
  g_march<MODE, true>(in, out, n0, N, L, T, lane, g, a, xp, yp);
}

// ---- host ------------------------------------------------------------------
static void pick_SL(int T, int N, int S0, int* Sp, int* Lp) {
  int Kmin = T / N, Kmax = (T + N - 1) / N;
  int S = S0;
  for (; S > 1; --S) {
    int L = (Kmax + S - 1) / S;
    if ((S - 1) * L <= Kmin) break;
  }
  *Sp = S;
  *Lp = (Kmax + *Sp - 1) / *Sp;
}

static float pow_f(float a, int n) {
  double p = 1.0;
  for (int i = 0; i < n; ++i) p *= (double)a;
  return (float)p;
}

extern "C" void kernel_launch(void* const* d_in, const int* in_sizes, int n_in,
                              void* d_out, int out_size, void* d_ws, size_t ws_size,
                              hipStream_t stream) {
  float* out = (float*)d_out;
  float* ws  = (float*)d_ws;
  const float* x = (const float*)d_in[0];
  const int T = in_sizes[0] / W;          // 131072

  if (T == 131072) {
    h2* sb16 = (h2*)ws;                   // fp16 s buffer: T*64 h2 = 32 MiB

    const fv2* x2 = (const fv2*)x;
    fv2* o2 = (fv2*)out;

    // comb1 N=1116 (K=118): L=15, fused s-generation (write out)
    hipLaunchKernelGGL((fcomb1<8, 15, 2, 4>), dim3(1024), dim3(512),
                       0, stream, x2, sb16, o2, 1116, 0.84f,
                       pow_f(0.84f, 15), T);
    // comb2 N=1188 (K=111): L=14 (RMW)
    hipLaunchKernelGGL((fcombh<8, 14, 8, 4>), dim3(1024), dim3(512),
                       0, stream, (const h2*)sb16, o2, 1188, 0.82f,
                       pow_f(0.82f, 14), T);
    // comb3 N=1277 (K=103): L=13 (RMW)
    hipLaunchKernelGGL((fcombh<8, 13, 8, 4>), dim3(1024), dim3(512),
                       0, stream, (const h2*)sb16, o2, 1277, 0.80f,
                       pow_f(0.80f, 13), T);
    // comb4 N=1356 (K=97): L=13 (RMW)
    hipLaunchKernelGGL((fcombh<8, 13, 8, 4>), dim3(1024), dim3(512),
                       0, stream, (const h2*)sb16, o2, 1356, 0.78f,
                       pow_f(0.78f, 13), T);
  } else {
    const int   apN[4] = {225, 556, 441, 341};
    const int   cbN[4] = {1116, 1188, 1277, 1356};
    const float cbG[4] = {0.84f, 0.82f, 0.80f, 0.78f};
    const float2* src = (const float2*)x;
    float2* bufs[2] = {(float2*)out, (float2*)ws};
    int cur = 0;
    for (int i = 0; i < 4; ++i) {
      int S, L;
      pick_SL(T, apN[i], 16, &S, &L);
      hipLaunchKernelGGL((stage_gen<0>), dim3(apN[i]), dim3(S * 64), 0, stream,
                         src, bufs[cur], apN[i], 0.7f, pow_f(-0.7f, L), L, T);
      src = bufs[cur];
      cur ^= 1;
    }
    float2* dst = (src == (float2*)out) ? (float2*)ws : (float2*)out;
    for (int i = 0; i < 4; ++i) {
      int S, L;
      pick_SL(T, cbN[i], 16, &S, &L);
      if (i == 0)
        hipLaunchKernelGGL((stage_gen<1>), dim3(cbN[i]), dim3(S * 64), 0, stream,
                           src, dst, cbN[i], cbG[i], pow_f(cbG[i], L), L, T);
      else
        hipLaunchKernelGGL((stage_gen<2>), dim3(cbN[i]), dim3(S * 64), 0, stream,
                           src, dst, cbN[i], cbG[i], pow_f(cbG[i], L), L, T);
    }
    if (dst != (float2*)out)
      hipMemcpyAsync(out, dst, (size_t)T * W * sizeof(float),
                     hipMemcpyDeviceToDevice, stream);
  }
}